// Round 4
// baseline (388.113 us; speedup 1.0000x reference)
//
#include <hip/hip_runtime.h>

#define NN 4096
#define IDX_CAP 512
#define SEG_CAP 160
#define SLOPE 0.2f

typedef float f4_t __attribute__((ext_vector_type(4)));

// ---- workspace layout (float offsets unless noted) ----
#define V_OFF     0                        // v1i,v2i,v1s,v2s : 4*128
#define C_OFF     512                      // 4 score constants
#define BT_OFF    516                      // b_total[128]
#define S_OFF     1024                     // s1i,s2i,s1s,s2s : 4*4096
#define HXI_OFF   32768                    // Ld@x   [4096,128]
#define HXS_OFF   (HXI_OFF + NN*128)       // Lu@x
#define UI_OFF    (HXS_OFF + NN*128)       // x@Wi0 + Hxi@Wi1
#define US_OFF    (UI_OFF + NN*128)        // x@Ws0 + Hxs@Ws1
#define XWH_OFF   (US_OFF + NN*128)        // x@Wh
#define OI_OFF    (XWH_OFF + NN*128)       // alpha_irr @ U_irr
#define OS_OFF    (OI_OFF + NN*128)        // alpha_sol @ U_sol
#define ZP_OFF    (OS_OFF + NN*128)        // P@xWh split-K partials: 8 * [4096,128]
#define WS_FLOATS (ZP_OFF + 8*NN*128)
#define IDX_BYTE_OFF ((size_t)WS_FLOATS * 4)                  // u16 idx lists: 2*4096*512
#define CNT_BYTE_OFF (IDX_BYTE_OFF + (size_t)2*NN*IDX_CAP*2)  // int counts: 2*4096
// total ws ≈ 38.2 MiB

// Pad map: insert 4 floats after every 32 -> float4 reads at stride 8 floats
// drop from 4-way to 2-way bank aliasing (2-way is free, m136).
#define XI(c)   ((c) + (((c) >> 5) << 2))   // [0,128) -> [0,140)

// XCD-aware (row,branch) mapping for the sparse kernels.
#define MAP_BR(bid)   (((bid) >> 2) & 1)
#define MAP_ROW(bid)  ((((bid) >> 3) << 2) | ((bid) & 3))

// ---------------------------------------------------------------------------
// Prep: v-vectors so s1[i] = x[i,:]·v + c, b_total.
__global__ __launch_bounds__(128) void k_prep(
    const float* __restrict__ Wi_w, const float* __restrict__ Wi_b,
    const float* __restrict__ Ws_w, const float* __restrict__ Ws_b,
    const float* __restrict__ Wh_b, const float* __restrict__ att_irr,
    const float* __restrict__ att_sol, float* __restrict__ ws) {
  const int t = threadIdx.x;
  float v1i = 0.f, v2i = 0.f, v1s = 0.f, v2s = 0.f;
  for (int j = 0; j < 2; ++j) {
    for (int o = 0; o < 128; ++o) {
      const float wi = Wi_w[j*16384 + t*128 + o];
      const float wv = Ws_w[j*16384 + t*128 + o];
      v1i += wi * att_irr[j*128 + o];
      v2i += wi * att_irr[256 + j*128 + o];
      v1s += wv * att_sol[j*128 + o];
      v2s += wv * att_sol[256 + j*128 + o];
    }
  }
  ws[V_OFF + t]       = v1i;
  ws[V_OFF + 128 + t] = v2i;
  ws[V_OFF + 256 + t] = v1s;
  ws[V_OFF + 384 + t] = v2s;
  ws[BT_OFF + t] = Wi_b[t] + Wi_b[128 + t] + Ws_b[t] + Ws_b[128 + t] + Wh_b[t];
  if (t < 4) {
    const float* bb = (t < 2) ? Wi_b : Ws_b;
    const float* aa = ((t < 2) ? att_irr : att_sol) + ((t & 1) ? 256 : 0);
    float c = 0.f;
    for (int k = 0; k < 256; ++k) c += bb[k] * aa[k];
    ws[C_OFF + t] = c;
  }
}

// ---------------------------------------------------------------------------
// Fused pre-pass: blocks 0..127 compute xWh = x@Wh; blocks 128..1151 scores.
__global__ __launch_bounds__(256) void k_pre2(
    const float* __restrict__ x, const float* __restrict__ Wh_w,
    float* __restrict__ ws) {
  __shared__ __align__(16) float At[32][33];
  __shared__ __align__(16) float Wt[32][144];
  const int t = threadIdx.x;

  if (blockIdx.x < 128) {
    const int rb = blockIdx.x;
    float* out = ws + XWH_OFF;
    const int rg = t >> 4, cg = t & 15;
    const int r0 = rb * 32;
    float acc[2][8];
    #pragma unroll
    for (int i = 0; i < 2; ++i)
      #pragma unroll
      for (int j = 0; j < 8; ++j) acc[i][j] = 0.f;
    for (int k0 = 0; k0 < 128; k0 += 32) {
      __syncthreads();
      {
        const int row = t >> 3, kq = t & 7;
        const float4 av = *(const float4*)&x[(r0 + row)*128 + k0 + kq*4];
        At[row][kq*4+0] = av.x; At[row][kq*4+1] = av.y;
        At[row][kq*4+2] = av.z; At[row][kq*4+3] = av.w;
      }
      #pragma unroll
      for (int l = 0; l < 4; ++l) {
        const int idx = t + l*256;
        const int kr = idx >> 5, c4 = idx & 31;
        const float4 wv = *(const float4*)&Wh_w[(k0 + kr)*128 + c4*4];
        *(float4*)&Wt[kr][XI(c4*4)] = wv;
      }
      __syncthreads();
      #pragma unroll
      for (int k = 0; k < 32; ++k) {
        const float a0 = At[rg*2 + 0][k];
        const float a1 = At[rg*2 + 1][k];
        const float4 b0 = *(const float4*)&Wt[k][XI(cg*8)];
        const float4 b1 = *(const float4*)&Wt[k][XI(cg*8 + 4)];
        acc[0][0] += a0*b0.x; acc[0][1] += a0*b0.y; acc[0][2] += a0*b0.z; acc[0][3] += a0*b0.w;
        acc[0][4] += a0*b1.x; acc[0][5] += a0*b1.y; acc[0][6] += a0*b1.z; acc[0][7] += a0*b1.w;
        acc[1][0] += a1*b0.x; acc[1][1] += a1*b0.y; acc[1][2] += a1*b0.z; acc[1][3] += a1*b0.w;
        acc[1][4] += a1*b1.x; acc[1][5] += a1*b1.y; acc[1][6] += a1*b1.z; acc[1][7] += a1*b1.w;
      }
    }
    #pragma unroll
    for (int i = 0; i < 2; ++i) {
      const int r = r0 + rg*2 + i;
      #pragma unroll
      for (int j = 0; j < 8; ++j) out[r*128 + cg*8 + j] = acc[i][j];
    }
  } else {
    const int wave = t >> 6, lane = t & 63;
    const int row = (blockIdx.x - 128) * 4 + wave;
    const float* v = ws + V_OFF;
    const float x0 = x[row*128 + lane];
    const float x1 = x[row*128 + 64 + lane];
    float p0 = x0 * v[lane]       + x1 * v[64 + lane];
    float p1 = x0 * v[128 + lane] + x1 * v[192 + lane];
    float p2 = x0 * v[256 + lane] + x1 * v[320 + lane];
    float p3 = x0 * v[384 + lane] + x1 * v[448 + lane];
    #pragma unroll
    for (int off = 32; off; off >>= 1) {
      p0 += __shfl_down(p0, off);
      p1 += __shfl_down(p1, off);
      p2 += __shfl_down(p2, off);
      p3 += __shfl_down(p3, off);
    }
    if (lane == 0) {
      ws[S_OFF + row]          = p0 + ws[C_OFF + 0];
      ws[S_OFF + NN + row]     = p1 + ws[C_OFF + 1];
      ws[S_OFF + 2*NN + row]   = p2 + ws[C_OFF + 2];
      ws[S_OFF + 3*NN + row]   = p3 + ws[C_OFF + 3];
    }
  }
}

// ---------------------------------------------------------------------------
// Sparse row pass: per-wave register-base compaction, nt scan, float4
// pair-gather (2 nnz per wave-iter), unroll 8, XCD-aware branch mapping.
__global__ __launch_bounds__(256) void k_spmm_emit(
    const float* __restrict__ Ld, const float* __restrict__ Lu,
    const float* __restrict__ x, float* __restrict__ ws,
    unsigned short* __restrict__ idxbuf, int* __restrict__ cntbuf) {
  const int bid = blockIdx.x;
  const int br  = MAP_BR(bid);
  const int row = MAP_ROW(bid);
  const float* __restrict__ Lrow = (br ? Lu : Ld) + (size_t)row * NN;
  float* __restrict__ Hx = ws + (br ? HXS_OFF : HXI_OFF);
  unsigned short* __restrict__ idxg = idxbuf + (size_t)(br*NN + row) * IDX_CAP;
  const int t = threadIdx.x;
  const int w = t >> 6, lane = t & 63;
  const unsigned long long lmask = (1ull << lane) - 1ull;

  __shared__ short jseg[4][SEG_CAP];
  __shared__ float vseg[4][SEG_CAP];
  __shared__ int   wcnt[4];
  __shared__ int   off[5];
  __shared__ short jl[IDX_CAP];
  __shared__ float vl[IDX_CAP];
  __shared__ float red[4][128];

  // ---- scan 16 KB row: 4 nt float4 per thread ----
  const f4_t* __restrict__ Lrow4 = (const f4_t*)Lrow;
  f4_t lv[4];
  #pragma unroll
  for (int i = 0; i < 4; ++i) lv[i] = __builtin_nontemporal_load(&Lrow4[i*256 + t]);

  int base = 0;
  #pragma unroll
  for (int i = 0; i < 4; ++i) {
    #pragma unroll
    for (int c = 0; c < 4; ++c) {
      const float v = lv[i][c];
      const unsigned long long bm = __ballot(v != 0.f);
      if (v != 0.f) {
        const int pos = base + (int)__popcll(bm & lmask);
        if (pos < SEG_CAP) {
          jseg[w][pos] = (short)((i*256 + t)*4 + c);
          vseg[w][pos] = v;
        }
      }
      base += (int)__popcll(bm);
    }
  }
  if (lane == 0) wcnt[w] = base;
  __syncthreads();
  if (t == 0) {
    int o = 0, ov = 0;
    #pragma unroll
    for (int s = 0; s < 4; ++s) { off[s] = o; ov |= (wcnt[s] > SEG_CAP); o += wcnt[s]; }
    off[4] = (ov || o > IDX_CAP) ? (IDX_CAP + 1) : o;
    cntbuf[br*NN + row] = off[4];
  }
  __syncthreads();
  const int m = off[4];

  if (m <= IDX_CAP) {
    const int o = off[w], c = wcnt[w];
    for (int k = lane; k < c; k += 64) {
      const short j = jseg[w][k];
      jl[o + k] = j;
      vl[o + k] = vseg[w][k];
      idxg[o + k] = (unsigned short)j;
    }
  }
  __syncthreads();

  if (m <= IDX_CAP) {
    // ---- gather: float4/lane, 2 nnz per wave-iter, 8 outstanding ----
    const f4_t* __restrict__ x4 = (const f4_t*)x;
    const int li = lane & 31, half = lane >> 5;
    f4_t acc = {0.f, 0.f, 0.f, 0.f};
    int p = w;   // pair index; wave w owns pairs == w (mod 4)
    for (; 2*(p + 28) + 1 < m; p += 32) {
      int jj[8]; float vv[8];
      #pragma unroll
      for (int u = 0; u < 8; ++u) {
        const int q = 2*(p + 4*u) + half;
        jj[u] = jl[q]; vv[u] = vl[q];
      }
      f4_t gg[8];
      #pragma unroll
      for (int u = 0; u < 8; ++u) gg[u] = x4[jj[u]*32 + li];
      #pragma unroll
      for (int u = 0; u < 8; ++u) acc += vv[u] * gg[u];
    }
    for (; 2*(p + 12) + 1 < m; p += 16) {
      int jj[4]; float vv[4];
      #pragma unroll
      for (int u = 0; u < 4; ++u) {
        const int q = 2*(p + 4*u) + half;
        jj[u] = jl[q]; vv[u] = vl[q];
      }
      f4_t gg[4];
      #pragma unroll
      for (int u = 0; u < 4; ++u) gg[u] = x4[jj[u]*32 + li];
      #pragma unroll
      for (int u = 0; u < 4; ++u) acc += vv[u] * gg[u];
    }
    for (; 2*p < m; p += 4) {
      const int q = 2*p + half;
      if (q < m) acc += vl[q] * x4[jl[q]*32 + li];
    }
    #pragma unroll
    for (int c = 0; c < 4; ++c) acc[c] += __shfl_xor(acc[c], 32);
    if (half == 0) {
      red[w][li*4+0] = acc[0]; red[w][li*4+1] = acc[1];
      red[w][li*4+2] = acc[2]; red[w][li*4+3] = acc[3];
    }
  } else {
    // overflow fallback (statistically impossible at 5%): dense rescan
    const float2* __restrict__ x2 = (const float2*)x;
    float acc0 = 0.f, acc1 = 0.f;
    for (int j = w*1024; j < (w+1)*1024; ++j) {
      const float v = Lrow[j];
      if (v != 0.f) {
        const float2 g = x2[j*64 + lane];
        acc0 += v*g.x; acc1 += v*g.y;
      }
    }
    red[w][lane*2]     = acc0;
    red[w][lane*2 + 1] = acc1;
  }
  __syncthreads();
  if (t < 128)
    Hx[row*128 + t] = red[0][t] + red[1][t] + red[2][t] + red[3][t];
}

// ---------------------------------------------------------------------------
// U-GEMMs: U_irr = x@Wi0 + Hxi@Wi1 ; U_sol = x@Ws0 + Hxs@Ws1 (padded Wt).
__global__ __launch_bounds__(256) void k_ugemm(
    const float* __restrict__ x, const float* __restrict__ Wi_w,
    const float* __restrict__ Ws_w, float* __restrict__ ws) {
  const int rb = blockIdx.x;
  const int sel = blockIdx.y;      // 0:U_irr 1:U_sol
  const float* A[2]; const float* W[2]; float* out;
  if (sel == 0) { A[0]=x; W[0]=Wi_w; A[1]=ws+HXI_OFF; W[1]=Wi_w+16384; out=ws+UI_OFF; }
  else          { A[0]=x; W[0]=Ws_w; A[1]=ws+HXS_OFF; W[1]=Ws_w+16384; out=ws+US_OFF; }

  __shared__ __align__(16) float At[32][33];
  __shared__ __align__(16) float Wt[32][144];
  const int t = threadIdx.x;
  const int rg = t >> 4, cg = t & 15;
  const int r0 = rb * 32;
  float acc[2][8];
  #pragma unroll
  for (int i = 0; i < 2; ++i)
    #pragma unroll
    for (int j = 0; j < 8; ++j) acc[i][j] = 0.f;

  for (int ps = 0; ps < 2; ++ps) {
    const float* __restrict__ Ap = A[ps];
    const float* __restrict__ Wp = W[ps];
    for (int k0 = 0; k0 < 128; k0 += 32) {
      __syncthreads();
      {
        const int row = t >> 3, kq = t & 7;
        const float4 av = *(const float4*)&Ap[(r0 + row)*128 + k0 + kq*4];
        At[row][kq*4+0] = av.x; At[row][kq*4+1] = av.y;
        At[row][kq*4+2] = av.z; At[row][kq*4+3] = av.w;
      }
      #pragma unroll
      for (int l = 0; l < 4; ++l) {
        const int idx = t + l*256;
        const int kr = idx >> 5, c4 = idx & 31;
        const float4 wv = *(const float4*)&Wp[(k0 + kr)*128 + c4*4];
        *(float4*)&Wt[kr][XI(c4*4)] = wv;
      }
      __syncthreads();
      #pragma unroll
      for (int k = 0; k < 32; ++k) {
        const float a0 = At[rg*2 + 0][k];
        const float a1 = At[rg*2 + 1][k];
        const float4 b0 = *(const float4*)&Wt[k][XI(cg*8)];
        const float4 b1 = *(const float4*)&Wt[k][XI(cg*8 + 4)];
        acc[0][0] += a0*b0.x; acc[0][1] += a0*b0.y; acc[0][2] += a0*b0.z; acc[0][3] += a0*b0.w;
        acc[0][4] += a0*b1.x; acc[0][5] += a0*b1.y; acc[0][6] += a0*b1.z; acc[0][7] += a0*b1.w;
        acc[1][0] += a1*b0.x; acc[1][1] += a1*b0.y; acc[1][2] += a1*b0.z; acc[1][3] += a1*b0.w;
        acc[1][4] += a1*b1.x; acc[1][5] += a1*b1.y; acc[1][6] += a1*b1.z; acc[1][7] += a1*b1.w;
      }
    }
  }
  #pragma unroll
  for (int i = 0; i < 2; ++i) {
    const int r = r0 + rg*2 + i;
    #pragma unroll
    for (int j = 0; j < 8; ++j) out[r*128 + cg*8 + j] = acc[i][j];
  }
}

// ---------------------------------------------------------------------------
// Masked-softmax attention: float4 pair-gather, unroll 8, XCD branch mapping.
__global__ __launch_bounds__(256) void k_attn(
    const float* __restrict__ Ld, const float* __restrict__ Lu,
    float* __restrict__ ws, const unsigned short* __restrict__ idxbuf,
    const int* __restrict__ cntbuf) {
  const int bid = blockIdx.x;
  const int br  = MAP_BR(bid);
  const int row = MAP_ROW(bid);
  const float* __restrict__ U = ws + (br ? US_OFF : UI_OFF);
  float* __restrict__ O = ws + (br ? OS_OFF : OI_OFF);
  const float s1 = ws[S_OFF + (br ? 2*NN : 0) + row];
  const float* __restrict__ s2a = ws + S_OFF + (br ? 3*NN : NN);
  const int cnt = cntbuf[br*NN + row];
  const int t = threadIdx.x;
  const int w = t >> 6, lane = t & 63;

  __shared__ int   jl[IDX_CAP];
  __shared__ float el[IDX_CAP];
  __shared__ float red[4][128];
  __shared__ float rsum[256];
  __shared__ float dsh[4];

  if (cnt > 0 && cnt <= IDX_CAP) {
    const unsigned short* __restrict__ idx = idxbuf + (size_t)(br*NN + row) * IDX_CAP;
    float dpart = 0.f;
    for (int p = t; p < cnt; p += 256) {
      const int j = idx[p];
      const float sc = s1 + s2a[j];
      const float e = expf(sc >= 0.f ? sc : SLOPE * sc);
      jl[p] = j; el[p] = e; dpart += e;
    }
    rsum[t] = dpart;
    __syncthreads();
    if (t < 128) rsum[t] += rsum[t + 128];
    __syncthreads();
    if (t < 64) {
      float v = rsum[t] + rsum[t + 64];
      #pragma unroll
      for (int off = 32; off; off >>= 1) v += __shfl_down(v, off);
      if (t == 0) dsh[0] = v;
    }
    __syncthreads();
    const float den = dsh[0];
    // ---- gather: float4/lane, 2 nnz per wave-iter, 8 outstanding ----
    const f4_t* __restrict__ U4 = (const f4_t*)U;
    const int li = lane & 31, half = lane >> 5;
    f4_t acc = {0.f, 0.f, 0.f, 0.f};
    int p = w;
    for (; 2*(p + 28) + 1 < cnt; p += 32) {
      int jj[8]; float ee[8];
      #pragma unroll
      for (int u = 0; u < 8; ++u) {
        const int q = 2*(p + 4*u) + half;
        jj[u] = jl[q]; ee[u] = el[q];
      }
      f4_t gg[8];
      #pragma unroll
      for (int u = 0; u < 8; ++u) gg[u] = U4[jj[u]*32 + li];
      #pragma unroll
      for (int u = 0; u < 8; ++u) acc += ee[u] * gg[u];
    }
    for (; 2*(p + 12) + 1 < cnt; p += 16) {
      int jj[4]; float ee[4];
      #pragma unroll
      for (int u = 0; u < 4; ++u) {
        const int q = 2*(p + 4*u) + half;
        jj[u] = jl[q]; ee[u] = el[q];
      }
      f4_t gg[4];
      #pragma unroll
      for (int u = 0; u < 4; ++u) gg[u] = U4[jj[u]*32 + li];
      #pragma unroll
      for (int u = 0; u < 4; ++u) acc += ee[u] * gg[u];
    }
    for (; 2*p < cnt; p += 4) {
      const int q = 2*p + half;
      if (q < cnt) acc += el[q] * U4[jl[q]*32 + li];
    }
    #pragma unroll
    for (int c = 0; c < 4; ++c) acc[c] += __shfl_xor(acc[c], 32);
    if (half == 0) {
      red[w][li*4+0] = acc[0]; red[w][li*4+1] = acc[1];
      red[w][li*4+2] = acc[2]; red[w][li*4+3] = acc[3];
    }
    __syncthreads();
    if (t < 128)
      O[row*128 + t] = (red[0][t] + red[1][t] + red[2][t] + red[3][t]) / den;
  } else if (cnt == 0) {
    // all-masked row -> uniform 1/N (never hit at 5%)
    const float2* __restrict__ U2 = (const float2*)U;
    float acc0 = 0.f, acc1 = 0.f;
    for (int j = w*1024; j < (w+1)*1024; ++j) {
      const float2 g = U2[j*64 + lane];
      acc0 += g.x; acc1 += g.y;
    }
    red[w][lane*2]     = acc0;
    red[w][lane*2 + 1] = acc1;
    __syncthreads();
    if (t < 128)
      O[row*128 + t] = (red[0][t] + red[1][t] + red[2][t] + red[3][t]) * (1.f / NN);
  } else {
    // overflowed index cap: dense rescan
    const float* __restrict__ Lrow = (br ? Lu : Ld) + (size_t)row * NN;
    const float2* __restrict__ U2 = (const float2*)U;
    float acc0 = 0.f, acc1 = 0.f, dp = 0.f;
    for (int j = w*1024; j < (w+1)*1024; ++j) {
      const float v = Lrow[j];
      if (v != 0.f) {
        const float sc = s1 + s2a[j];
        const float e = expf(sc >= 0.f ? sc : SLOPE * sc);
        const float2 g = U2[j*64 + lane];
        acc0 += e*g.x; acc1 += e*g.y;
        dp += e;
      }
    }
    if (lane == 0) dsh[w] = dp;
    red[w][lane*2]     = acc0;
    red[w][lane*2 + 1] = acc1;
    __syncthreads();
    const float den = dsh[0] + dsh[1] + dsh[2] + dsh[3];
    if (t < 128)
      O[row*128 + t] = (red[0][t] + red[1][t] + red[2][t] + red[3][t]) / den;
  }
}

// ---------------------------------------------------------------------------
// Dense P @ xWh v3: BM=128, BN=128, BK=32, split-K=8, 256 threads, 8x8 tile.
// Per k-iter per wave: 8 broadcast a-reads (ds_read2-pairable) + 2 b128 reads
// vs 128 FMA cycles -> FMA-issue-dominated (ceiling ~73% VALU).
__global__ __launch_bounds__(256) void k_pgemm(const float* __restrict__ P,
                                               const float* __restrict__ ws,
                                               float* __restrict__ zpart) {
  const int rbl = blockIdx.x;   // 32 row-blocks of 128
  const int kz  = blockIdx.y;   // 8 K-splits of 512
  const float* __restrict__ Xw = ws + XWH_OFF;

  __shared__ __align__(16) float Pt[128][33];
  __shared__ __align__(16) float Xt[32][144];
  const int t = threadIdx.x;
  const int rg = t >> 4, cg = t & 15;   // 16 x 8 rows, 16 x 8 cols
  const int r0 = rbl * 128;
  const int kbase = kz * 512;
  float acc[8][8];
  #pragma unroll
  for (int i = 0; i < 8; ++i)
    #pragma unroll
    for (int j = 0; j < 8; ++j) acc[i][j] = 0.f;

  for (int k0 = kbase; k0 < kbase + 512; k0 += 32) {
    __syncthreads();
    #pragma unroll
    for (int l = 0; l < 4; ++l) { // stage P: 128x32 (writes <=2-way)
      const int idx = t + l*256;
      const int row = idx >> 3, kq = idx & 7;
      const float4 pv = *(const float4*)&P[(size_t)(r0 + row)*NN + k0 + kq*4];
      Pt[row][kq*4+0] = pv.x; Pt[row][kq*4+1] = pv.y;
      Pt[row][kq*4+2] = pv.z; Pt[row][kq*4+3] = pv.w;
    }
    #pragma unroll
    for (int l = 0; l < 4; ++l) { // stage xWh: 32x128 (padded layout)
      const int idx = t + l*256;
      const int kr = idx >> 5, c4 = idx & 31;
      const float4 xv = *(const float4*)&Xw[(k0 + kr)*128 + c4*4];
      *(float4*)&Xt[kr][XI(c4*4)] = xv;
    }
    __syncthreads();
    #pragma unroll
    for (int k = 0; k < 32; ++k) {
      float a[8];
      #pragma unroll
      for (int i = 0; i < 8; ++i) a[i] = Pt[rg*8 + i][k];   // broadcast reads
      const float4 b0 = *(const float4*)&Xt[k][XI(cg*8)];
      const float4 b1 = *(const float4*)&Xt[k][XI(cg*8 + 4)];
      #pragma unroll
      for (int i = 0; i < 8; ++i) {
        acc[i][0] += a[i]*b0.x; acc[i][1] += a[i]*b0.y;
        acc[i][2] += a[i]*b0.z; acc[i][3] += a[i]*b0.w;
        acc[i][4] += a[i]*b1.x; acc[i][5] += a[i]*b1.y;
        acc[i][6] += a[i]*b1.z; acc[i][7] += a[i]*b1.w;
      }
    }
  }
  float* __restrict__ zp = zpart + (size_t)kz * NN * 128;
  #pragma unroll
  for (int i = 0; i < 8; ++i) {
    const int r = r0 + rg*8 + i;
    float4 o0, o1;
    o0.x = acc[i][0]; o0.y = acc[i][1]; o0.z = acc[i][2]; o0.w = acc[i][3];
    o1.x = acc[i][4]; o1.y = acc[i][5]; o1.z = acc[i][6]; o1.w = acc[i][7];
    *(float4*)&zp[r*128 + cg*8]     = o0;
    *(float4*)&zp[r*128 + cg*8 + 4] = o1;
  }
}

// ---------------------------------------------------------------------------
// z = O_irr + O_sol + sum_k zpart[k] + b_total
__global__ __launch_bounds__(256) void k_combine(const float* __restrict__ ws,
                                                 float* __restrict__ z) {
  const int i = blockIdx.x * 256 + threadIdx.x;
  const int col = i & 127;
  float acc = ws[BT_OFF + col] + ws[OI_OFF + i] + ws[OS_OFF + i];
  #pragma unroll
  for (int kz = 0; kz < 8; ++kz) acc += ws[ZP_OFF + kz*NN*128 + i];
  z[i] = acc;
}

// ---------------------------------------------------------------------------
extern "C" void kernel_launch(void* const* d_in, const int* in_sizes, int n_in,
                              void* d_out, int out_size, void* d_ws, size_t ws_size,
                              hipStream_t stream) {
  const float* x       = (const float*)d_in[0];
  const float* Lu      = (const float*)d_in[1];
  const float* Ld      = (const float*)d_in[2];
  const float* P       = (const float*)d_in[3];
  const float* Wi_w    = (const float*)d_in[4];
  const float* Wi_b    = (const float*)d_in[5];
  const float* Ws_w    = (const float*)d_in[6];
  const float* Ws_b    = (const float*)d_in[7];
  const float* Wh_w    = (const float*)d_in[8];
  const float* Wh_b    = (const float*)d_in[9];
  const float* att_irr = (const float*)d_in[10];
  const float* att_sol = (const float*)d_in[11];
  float* z  = (float*)d_out;
  float* ws = (float*)d_ws;
  unsigned short* idxbuf = (unsigned short*)((char*)d_ws + IDX_BYTE_OFF);
  int*            cntbuf = (int*)((char*)d_ws + CNT_BYTE_OFF);
  float*          zpart  = ws + ZP_OFF;

  k_prep<<<1, 128, 0, stream>>>(Wi_w, Wi_b, Ws_w, Ws_b, Wh_b, att_irr, att_sol, ws);
  k_pre2<<<1152, 256, 0, stream>>>(x, Wh_w, ws);
  k_spmm_emit<<<2 * NN, 256, 0, stream>>>(Ld, Lu, x, ws, idxbuf, cntbuf);
  {
    dim3 g(128, 2);
    k_ugemm<<<g, 256, 0, stream>>>(x, Wi_w, Ws_w, ws);
  }
  k_attn<<<2 * NN, 256, 0, stream>>>(Ld, Lu, ws, idxbuf, cntbuf);
  {
    dim3 g(32, 8);
    k_pgemm<<<g, 256, 0, stream>>>(P, ws, zpart);
  }
  k_combine<<<NN * 128 / 256, 256, 0, stream>>>(ws, z);
}

// Round 5
// 362.498 us; speedup vs baseline: 1.0707x; 1.0707x over previous
//
#include <hip/hip_runtime.h>

#define NN 4096
#define IDX_CAP 512
#define SEG_CAP 160
#define SLOPE 0.2f

typedef float f4_t __attribute__((ext_vector_type(4)));
typedef __bf16 bf8v __attribute__((ext_vector_type(8)));
typedef float f32x16 __attribute__((ext_vector_type(16)));

// ---- workspace layout (float offsets unless noted) ----
#define V_OFF     0                        // v1i,v2i,v1s,v2s : 4*128
#define C_OFF     512                      // 4 score constants
#define BT_OFF    516                      // b_total[128]
#define S_OFF     1024                     // s1i,s2i,s1s,s2s : 4*4096
#define HXI_OFF   32768                    // Ld@x   [4096,128]
#define HXS_OFF   (HXI_OFF + NN*128)       // Lu@x
#define UI_OFF    (HXS_OFF + NN*128)       // x@Wi0 + Hxi@Wi1
#define US_OFF    (UI_OFF + NN*128)        // x@Ws0 + Hxs@Ws1
#define XWH_OFF   (US_OFF + NN*128)        // REUSED: xwhT hi/lo bf16 [128][4096] each (2 MB total)
#define OI_OFF    (XWH_OFF + NN*128)       // alpha_irr @ U_irr
#define OS_OFF    (OI_OFF + NN*128)        // alpha_sol @ U_sol
#define ZP_OFF    (OS_OFF + NN*128)        // P@xWh split-K partials: 8 * [4096,128]
#define WS_FLOATS (ZP_OFF + 8*NN*128)
#define IDX_BYTE_OFF ((size_t)WS_FLOATS * 4)                  // u16 idx lists: 2*4096*512
#define CNT_BYTE_OFF (IDX_BYTE_OFF + (size_t)2*NN*IDX_CAP*2)  // int counts: 2*4096

// Pad map: insert 4 floats after every 32 -> float4 reads at stride 8 floats
// drop from 4-way to 2-way bank aliasing (2-way is free, m136).
#define XI(c)   ((c) + (((c) >> 5) << 2))   // [0,128) -> [0,140)

// XCD-aware (row,branch) mapping for the sparse kernels.
#define MAP_BR(bid)   (((bid) >> 2) & 1)
#define MAP_ROW(bid)  ((((bid) >> 3) << 2) | ((bid) & 3))

// bf16 round-to-nearest-even helpers (bit math; no HIP bf16 header dependence)
__device__ __forceinline__ unsigned short f2bf(float x) {
  unsigned u = __float_as_uint(x);
  return (unsigned short)((u + 0x7FFFu + ((u >> 16) & 1u)) >> 16);
}
__device__ __forceinline__ float bf2f(unsigned short h) {
  return __uint_as_float(((unsigned)h) << 16);
}
union BFU { unsigned short u[8]; bf8v v; };

// ---------------------------------------------------------------------------
// Prep: v-vectors so s1[i] = x[i,:]·v + c, b_total.
__global__ __launch_bounds__(128) void k_prep(
    const float* __restrict__ Wi_w, const float* __restrict__ Wi_b,
    const float* __restrict__ Ws_w, const float* __restrict__ Ws_b,
    const float* __restrict__ Wh_b, const float* __restrict__ att_irr,
    const float* __restrict__ att_sol, float* __restrict__ ws) {
  const int t = threadIdx.x;
  float v1i = 0.f, v2i = 0.f, v1s = 0.f, v2s = 0.f;
  for (int j = 0; j < 2; ++j) {
    for (int o = 0; o < 128; ++o) {
      const float wi = Wi_w[j*16384 + t*128 + o];
      const float wv = Ws_w[j*16384 + t*128 + o];
      v1i += wi * att_irr[j*128 + o];
      v2i += wi * att_irr[256 + j*128 + o];
      v1s += wv * att_sol[j*128 + o];
      v2s += wv * att_sol[256 + j*128 + o];
    }
  }
  ws[V_OFF + t]       = v1i;
  ws[V_OFF + 128 + t] = v2i;
  ws[V_OFF + 256 + t] = v1s;
  ws[V_OFF + 384 + t] = v2s;
  ws[BT_OFF + t] = Wi_b[t] + Wi_b[128 + t] + Ws_b[t] + Ws_b[128 + t] + Wh_b[t];
  if (t < 4) {
    const float* bb = (t < 2) ? Wi_b : Ws_b;
    const float* aa = ((t < 2) ? att_irr : att_sol) + ((t & 1) ? 256 : 0);
    float c = 0.f;
    for (int k = 0; k < 256; ++k) c += bb[k] * aa[k];
    ws[C_OFF + t] = c;
  }
}

// ---------------------------------------------------------------------------
// Fused pre-pass: blocks 0..127 compute xWh = x@Wh -> write TRANSPOSED bf16
// hi/lo [128][4096] (feeds the MFMA pgemm); blocks 128..1151 compute scores.
__global__ __launch_bounds__(256) void k_pre2(
    const float* __restrict__ x, const float* __restrict__ Wh_w,
    float* __restrict__ ws, unsigned short* __restrict__ xth,
    unsigned short* __restrict__ xtl) {
  __shared__ __align__(16) float At[32][33];
  __shared__ __align__(16) float Wt[32][144];
  const int t = threadIdx.x;

  if (blockIdx.x < 128) {
    const int rb = blockIdx.x;
    const int rg = t >> 4, cg = t & 15;
    const int r0 = rb * 32;
    float acc[2][8];
    #pragma unroll
    for (int i = 0; i < 2; ++i)
      #pragma unroll
      for (int j = 0; j < 8; ++j) acc[i][j] = 0.f;
    for (int k0 = 0; k0 < 128; k0 += 32) {
      __syncthreads();
      {
        const int row = t >> 3, kq = t & 7;
        const float4 av = *(const float4*)&x[(r0 + row)*128 + k0 + kq*4];
        At[row][kq*4+0] = av.x; At[row][kq*4+1] = av.y;
        At[row][kq*4+2] = av.z; At[row][kq*4+3] = av.w;
      }
      #pragma unroll
      for (int l = 0; l < 4; ++l) {
        const int idx = t + l*256;
        const int kr = idx >> 5, c4 = idx & 31;
        const float4 wv = *(const float4*)&Wh_w[(k0 + kr)*128 + c4*4];
        *(float4*)&Wt[kr][XI(c4*4)] = wv;
      }
      __syncthreads();
      #pragma unroll
      for (int k = 0; k < 32; ++k) {
        const float a0 = At[rg*2 + 0][k];
        const float a1 = At[rg*2 + 1][k];
        const float4 b0 = *(const float4*)&Wt[k][XI(cg*8)];
        const float4 b1 = *(const float4*)&Wt[k][XI(cg*8 + 4)];
        acc[0][0] += a0*b0.x; acc[0][1] += a0*b0.y; acc[0][2] += a0*b0.z; acc[0][3] += a0*b0.w;
        acc[0][4] += a0*b1.x; acc[0][5] += a0*b1.y; acc[0][6] += a0*b1.z; acc[0][7] += a0*b1.w;
        acc[1][0] += a1*b0.x; acc[1][1] += a1*b0.y; acc[1][2] += a1*b0.z; acc[1][3] += a1*b0.w;
        acc[1][4] += a1*b1.x; acc[1][5] += a1*b1.y; acc[1][6] += a1*b1.z; acc[1][7] += a1*b1.w;
      }
    }
    #pragma unroll
    for (int i = 0; i < 2; ++i) {
      const int r = r0 + rg*2 + i;
      #pragma unroll
      for (int j = 0; j < 8; ++j) {
        const int c = cg*8 + j;
        const float val = acc[i][j];
        const unsigned short h = f2bf(val);
        const unsigned short l = f2bf(val - bf2f(h));
        xth[(size_t)c*NN + r] = h;
        xtl[(size_t)c*NN + r] = l;
      }
    }
  } else {
    const int wave = t >> 6, lane = t & 63;
    const int row = (blockIdx.x - 128) * 4 + wave;
    const float* v = ws + V_OFF;
    const float x0 = x[row*128 + lane];
    const float x1 = x[row*128 + 64 + lane];
    float p0 = x0 * v[lane]       + x1 * v[64 + lane];
    float p1 = x0 * v[128 + lane] + x1 * v[192 + lane];
    float p2 = x0 * v[256 + lane] + x1 * v[320 + lane];
    float p3 = x0 * v[384 + lane] + x1 * v[448 + lane];
    #pragma unroll
    for (int off = 32; off; off >>= 1) {
      p0 += __shfl_down(p0, off);
      p1 += __shfl_down(p1, off);
      p2 += __shfl_down(p2, off);
      p3 += __shfl_down(p3, off);
    }
    if (lane == 0) {
      ws[S_OFF + row]          = p0 + ws[C_OFF + 0];
      ws[S_OFF + NN + row]     = p1 + ws[C_OFF + 1];
      ws[S_OFF + 2*NN + row]   = p2 + ws[C_OFF + 2];
      ws[S_OFF + 3*NN + row]   = p3 + ws[C_OFF + 3];
    }
  }
}

// ---------------------------------------------------------------------------
// Sparse row pass (round-3 form): per-wave register-base compaction, nt scan,
// float4 pair-gather, XCD-aware branch mapping.
__global__ __launch_bounds__(256) void k_spmm_emit(
    const float* __restrict__ Ld, const float* __restrict__ Lu,
    const float* __restrict__ x, float* __restrict__ ws,
    unsigned short* __restrict__ idxbuf, int* __restrict__ cntbuf) {
  const int bid = blockIdx.x;
  const int br  = MAP_BR(bid);
  const int row = MAP_ROW(bid);
  const float* __restrict__ Lrow = (br ? Lu : Ld) + (size_t)row * NN;
  float* __restrict__ Hx = ws + (br ? HXS_OFF : HXI_OFF);
  unsigned short* __restrict__ idxg = idxbuf + (size_t)(br*NN + row) * IDX_CAP;
  const int t = threadIdx.x;
  const int w = t >> 6, lane = t & 63;
  const unsigned long long lmask = (1ull << lane) - 1ull;

  __shared__ short jseg[4][SEG_CAP];
  __shared__ float vseg[4][SEG_CAP];
  __shared__ int   wcnt[4];
  __shared__ int   off[5];
  __shared__ short jl[IDX_CAP];
  __shared__ float vl[IDX_CAP];
  __shared__ float red[4][128];

  const f4_t* __restrict__ Lrow4 = (const f4_t*)Lrow;
  f4_t lv[4];
  #pragma unroll
  for (int i = 0; i < 4; ++i) lv[i] = __builtin_nontemporal_load(&Lrow4[i*256 + t]);

  int base = 0;
  #pragma unroll
  for (int i = 0; i < 4; ++i) {
    #pragma unroll
    for (int c = 0; c < 4; ++c) {
      const float v = lv[i][c];
      const unsigned long long bm = __ballot(v != 0.f);
      if (v != 0.f) {
        const int pos = base + (int)__popcll(bm & lmask);
        if (pos < SEG_CAP) {
          jseg[w][pos] = (short)((i*256 + t)*4 + c);
          vseg[w][pos] = v;
        }
      }
      base += (int)__popcll(bm);
    }
  }
  if (lane == 0) wcnt[w] = base;
  __syncthreads();
  if (t == 0) {
    int o = 0, ov = 0;
    #pragma unroll
    for (int s = 0; s < 4; ++s) { off[s] = o; ov |= (wcnt[s] > SEG_CAP); o += wcnt[s]; }
    off[4] = (ov || o > IDX_CAP) ? (IDX_CAP + 1) : o;
    cntbuf[br*NN + row] = off[4];
  }
  __syncthreads();
  const int m = off[4];

  if (m <= IDX_CAP) {
    const int o = off[w], c = wcnt[w];
    for (int k = lane; k < c; k += 64) {
      const short j = jseg[w][k];
      jl[o + k] = j;
      vl[o + k] = vseg[w][k];
      idxg[o + k] = (unsigned short)j;
    }
  }
  __syncthreads();

  if (m <= IDX_CAP) {
    const f4_t* __restrict__ x4 = (const f4_t*)x;
    const int li = lane & 31, half = lane >> 5;
    f4_t acc = {0.f, 0.f, 0.f, 0.f};
    int p = w;
    for (; 2*(p + 12) + 1 < m; p += 16) {
      const int q0 = 2*p + half, q1 = 2*(p+4) + half,
                q2 = 2*(p+8) + half, q3 = 2*(p+12) + half;
      const int j0 = jl[q0], j1 = jl[q1], j2 = jl[q2], j3 = jl[q3];
      const float v0 = vl[q0], v1 = vl[q1], v2 = vl[q2], v3 = vl[q3];
      const f4_t g0 = x4[j0*32 + li];
      const f4_t g1 = x4[j1*32 + li];
      const f4_t g2 = x4[j2*32 + li];
      const f4_t g3 = x4[j3*32 + li];
      acc += v0*g0; acc += v1*g1; acc += v2*g2; acc += v3*g3;
    }
    for (; 2*p < m; p += 4) {
      const int q = 2*p + half;
      if (q < m) acc += vl[q] * x4[jl[q]*32 + li];
    }
    #pragma unroll
    for (int c = 0; c < 4; ++c) acc[c] += __shfl_xor(acc[c], 32);
    if (half == 0) {
      red[w][li*4+0] = acc[0]; red[w][li*4+1] = acc[1];
      red[w][li*4+2] = acc[2]; red[w][li*4+3] = acc[3];
    }
  } else {
    const float2* __restrict__ x2 = (const float2*)x;
    float acc0 = 0.f, acc1 = 0.f;
    for (int j = w*1024; j < (w+1)*1024; ++j) {
      const float v = Lrow[j];
      if (v != 0.f) {
        const float2 g = x2[j*64 + lane];
        acc0 += v*g.x; acc1 += v*g.y;
      }
    }
    red[w][lane*2]     = acc0;
    red[w][lane*2 + 1] = acc1;
  }
  __syncthreads();
  if (t < 128)
    Hx[row*128 + t] = red[0][t] + red[1][t] + red[2][t] + red[3][t];
}

// ---------------------------------------------------------------------------
// U-GEMMs: U_irr = x@Wi0 + Hxi@Wi1 ; U_sol = x@Ws0 + Hxs@Ws1 (padded Wt).
__global__ __launch_bounds__(256) void k_ugemm(
    const float* __restrict__ x, const float* __restrict__ Wi_w,
    const float* __restrict__ Ws_w, float* __restrict__ ws) {
  const int rb = blockIdx.x;
  const int sel = blockIdx.y;      // 0:U_irr 1:U_sol
  const float* A[2]; const float* W[2]; float* out;
  if (sel == 0) { A[0]=x; W[0]=Wi_w; A[1]=ws+HXI_OFF; W[1]=Wi_w+16384; out=ws+UI_OFF; }
  else          { A[0]=x; W[0]=Ws_w; A[1]=ws+HXS_OFF; W[1]=Ws_w+16384; out=ws+US_OFF; }

  __shared__ __align__(16) float At[32][33];
  __shared__ __align__(16) float Wt[32][144];
  const int t = threadIdx.x;
  const int rg = t >> 4, cg = t & 15;
  const int r0 = rb * 32;
  float acc[2][8];
  #pragma unroll
  for (int i = 0; i < 2; ++i)
    #pragma unroll
    for (int j = 0; j < 8; ++j) acc[i][j] = 0.f;

  for (int ps = 0; ps < 2; ++ps) {
    const float* __restrict__ Ap = A[ps];
    const float* __restrict__ Wp = W[ps];
    for (int k0 = 0; k0 < 128; k0 += 32) {
      __syncthreads();
      {
        const int row = t >> 3, kq = t & 7;
        const float4 av = *(const float4*)&Ap[(r0 + row)*128 + k0 + kq*4];
        At[row][kq*4+0] = av.x; At[row][kq*4+1] = av.y;
        At[row][kq*4+2] = av.z; At[row][kq*4+3] = av.w;
      }
      #pragma unroll
      for (int l = 0; l < 4; ++l) {
        const int idx = t + l*256;
        const int kr = idx >> 5, c4 = idx & 31;
        const float4 wv = *(const float4*)&Wp[(k0 + kr)*128 + c4*4];
        *(float4*)&Wt[kr][XI(c4*4)] = wv;
      }
      __syncthreads();
      #pragma unroll
      for (int k = 0; k < 32; ++k) {
        const float a0 = At[rg*2 + 0][k];
        const float a1 = At[rg*2 + 1][k];
        const float4 b0 = *(const float4*)&Wt[k][XI(cg*8)];
        const float4 b1 = *(const float4*)&Wt[k][XI(cg*8 + 4)];
        acc[0][0] += a0*b0.x; acc[0][1] += a0*b0.y; acc[0][2] += a0*b0.z; acc[0][3] += a0*b0.w;
        acc[0][4] += a0*b1.x; acc[0][5] += a0*b1.y; acc[0][6] += a0*b1.z; acc[0][7] += a0*b1.w;
        acc[1][0] += a1*b0.x; acc[1][1] += a1*b0.y; acc[1][2] += a1*b0.z; acc[1][3] += a1*b0.w;
        acc[1][4] += a1*b1.x; acc[1][5] += a1*b1.y; acc[1][6] += a1*b1.z; acc[1][7] += a1*b1.w;
      }
    }
  }
  #pragma unroll
  for (int i = 0; i < 2; ++i) {
    const int r = r0 + rg*2 + i;
    #pragma unroll
    for (int j = 0; j < 8; ++j) out[r*128 + cg*8 + j] = acc[i][j];
  }
}

// ---------------------------------------------------------------------------
// Masked-softmax attention (round-3 form): float4 pair-gather, XCD mapping.
__global__ __launch_bounds__(256) void k_attn(
    const float* __restrict__ Ld, const float* __restrict__ Lu,
    float* __restrict__ ws, const unsigned short* __restrict__ idxbuf,
    const int* __restrict__ cntbuf) {
  const int bid = blockIdx.x;
  const int br  = MAP_BR(bid);
  const int row = MAP_ROW(bid);
  const float* __restrict__ U = ws + (br ? US_OFF : UI_OFF);
  float* __restrict__ O = ws + (br ? OS_OFF : OI_OFF);
  const float s1 = ws[S_OFF + (br ? 2*NN : 0) + row];
  const float* __restrict__ s2a = ws + S_OFF + (br ? 3*NN : NN);
  const int cnt = cntbuf[br*NN + row];
  const int t = threadIdx.x;
  const int w = t >> 6, lane = t & 63;

  __shared__ int   jl[IDX_CAP];
  __shared__ float el[IDX_CAP];
  __shared__ float red[4][128];
  __shared__ float rsum[256];
  __shared__ float dsh[4];

  if (cnt > 0 && cnt <= IDX_CAP) {
    const unsigned short* __restrict__ idx = idxbuf + (size_t)(br*NN + row) * IDX_CAP;
    float dpart = 0.f;
    for (int p = t; p < cnt; p += 256) {
      const int j = idx[p];
      const float sc = s1 + s2a[j];
      const float e = expf(sc >= 0.f ? sc : SLOPE * sc);
      jl[p] = j; el[p] = e; dpart += e;
    }
    rsum[t] = dpart;
    __syncthreads();
    if (t < 128) rsum[t] += rsum[t + 128];
    __syncthreads();
    if (t < 64) {
      float v = rsum[t] + rsum[t + 64];
      #pragma unroll
      for (int off = 32; off; off >>= 1) v += __shfl_down(v, off);
      if (t == 0) dsh[0] = v;
    }
    __syncthreads();
    const float den = dsh[0];
    const f4_t* __restrict__ U4 = (const f4_t*)U;
    const int li = lane & 31, half = lane >> 5;
    f4_t acc = {0.f, 0.f, 0.f, 0.f};
    int p = w;
    for (; 2*(p + 12) + 1 < cnt; p += 16) {
      const int q0 = 2*p + half, q1 = 2*(p+4) + half,
                q2 = 2*(p+8) + half, q3 = 2*(p+12) + half;
      const int j0 = jl[q0], j1 = jl[q1], j2 = jl[q2], j3 = jl[q3];
      const float e0 = el[q0], e1 = el[q1], e2 = el[q2], e3 = el[q3];
      const f4_t g0 = U4[j0*32 + li];
      const f4_t g1 = U4[j1*32 + li];
      const f4_t g2 = U4[j2*32 + li];
      const f4_t g3 = U4[j3*32 + li];
      acc += e0*g0; acc += e1*g1; acc += e2*g2; acc += e3*g3;
    }
    for (; 2*p < cnt; p += 4) {
      const int q = 2*p + half;
      if (q < cnt) acc += el[q] * U4[jl[q]*32 + li];
    }
    #pragma unroll
    for (int c = 0; c < 4; ++c) acc[c] += __shfl_xor(acc[c], 32);
    if (half == 0) {
      red[w][li*4+0] = acc[0]; red[w][li*4+1] = acc[1];
      red[w][li*4+2] = acc[2]; red[w][li*4+3] = acc[3];
    }
    __syncthreads();
    if (t < 128)
      O[row*128 + t] = (red[0][t] + red[1][t] + red[2][t] + red[3][t]) / den;
  } else if (cnt == 0) {
    const float2* __restrict__ U2 = (const float2*)U;
    float acc0 = 0.f, acc1 = 0.f;
    for (int j = w*1024; j < (w+1)*1024; ++j) {
      const float2 g = U2[j*64 + lane];
      acc0 += g.x; acc1 += g.y;
    }
    red[w][lane*2]     = acc0;
    red[w][lane*2 + 1] = acc1;
    __syncthreads();
    if (t < 128)
      O[row*128 + t] = (red[0][t] + red[1][t] + red[2][t] + red[3][t]) * (1.f / NN);
  } else {
    const float* __restrict__ Lrow = (br ? Lu : Ld) + (size_t)row * NN;
    const float2* __restrict__ U2 = (const float2*)U;
    float acc0 = 0.f, acc1 = 0.f, dp = 0.f;
    for (int j = w*1024; j < (w+1)*1024; ++j) {
      const float v = Lrow[j];
      if (v != 0.f) {
        const float sc = s1 + s2a[j];
        const float e = expf(sc >= 0.f ? sc : SLOPE * sc);
        const float2 g = U2[j*64 + lane];
        acc0 += e*g.x; acc1 += e*g.y;
        dp += e;
      }
    }
    if (lane == 0) dsh[w] = dp;
    red[w][lane*2]     = acc0;
    red[w][lane*2 + 1] = acc1;
    __syncthreads();
    const float den = dsh[0] + dsh[1] + dsh[2] + dsh[3];
    if (t < 128)
      O[row*128 + t] = (red[0][t] + red[1][t] + red[2][t] + red[3][t]) / den;
  }
}

// ---------------------------------------------------------------------------
// Dense P @ xWh via MFMA (bf16 hi/lo split, 3 products: exact to ~1e-6).
// BM=64 (2 M-tiles of 32), N=128 (4 n-tiles), split-K=8; 4 waves = 2 M-tiles
// x 2 K-halves; barrier-free K-loop (A from HBM, B from L2-resident xwhT),
// one LDS reduction at block end. D-layout per m74/m101 (verified):
// col=lane&31, row=(reg&3)+8*(reg>>2)+4*(lane>>5).
__global__ __launch_bounds__(256) void k_pgemm(
    const float* __restrict__ P, const unsigned short* __restrict__ xth,
    const unsigned short* __restrict__ xtl, float* __restrict__ zpart) {
  const int t = threadIdx.x;
  const int w = t >> 6, lane = t & 63;
  const int mt = w & 1, kh = w >> 1;
  const int la = lane & 31;
  const int koff = (lane >> 5) * 8;
  const int r0 = blockIdx.x * 64;
  const int kz = blockIdx.y;
  const int kb = kz * 512 + kh * 256;    // this wave's 256-wide K chunk

  f32x16 acc[4];
  #pragma unroll
  for (int n = 0; n < 4; ++n)
    #pragma unroll
    for (int e = 0; e < 16; ++e) acc[n][e] = 0.f;

  const float* __restrict__ arow = P + (size_t)(r0 + 32*mt + la) * NN + kb + koff;

  for (int s = 0; s < 16; ++s) {           // 16 K-steps of 16 source columns
    const int kk = s * 16;
    const float4 a0 = *(const float4*)(arow + kk);
    const float4 a1 = *(const float4*)(arow + kk + 4);
    BFU ah, al;
    #pragma unroll
    for (int i = 0; i < 8; ++i) {
      const float f = (i < 4) ? (&a0.x)[i] : (&a1.x)[i - 4];
      const unsigned short h = f2bf(f);
      ah.u[i] = h;
      al.u[i] = f2bf(f - bf2f(h));
    }
    #pragma unroll
    for (int n = 0; n < 4; ++n) {
      const size_t boff = (size_t)(32*n + la) * NN + kb + kk + koff;
      const bf8v bh = *(const bf8v*)(xth + boff);
      const bf8v bl = *(const bf8v*)(xtl + boff);
      acc[n] = __builtin_amdgcn_mfma_f32_32x32x16_bf16(ah.v, bh, acc[n], 0, 0, 0);
      acc[n] = __builtin_amdgcn_mfma_f32_32x32x16_bf16(al.v, bh, acc[n], 0, 0, 0);
      acc[n] = __builtin_amdgcn_mfma_f32_32x32x16_bf16(ah.v, bl, acc[n], 0, 0, 0);
    }
  }

  // reduce the two K-half waves per M-tile via LDS, write zpart[kz]
  __shared__ float red[2][32][128];
  if (kh == 0) {
    #pragma unroll
    for (int n = 0; n < 4; ++n)
      #pragma unroll
      for (int reg = 0; reg < 16; ++reg) {
        const int row = (reg & 3) + 8*(reg >> 2) + 4*(lane >> 5);
        red[mt][row][32*n + la] = acc[n][reg];
      }
  }
  __syncthreads();
  if (kh == 1) {
    float* __restrict__ zp = zpart + (size_t)kz * NN * 128;
    #pragma unroll
    for (int n = 0; n < 4; ++n)
      #pragma unroll
      for (int reg = 0; reg < 16; ++reg) {
        const int row = (reg & 3) + 8*(reg >> 2) + 4*(lane >> 5);
        zp[(size_t)(r0 + 32*mt + row) * 128 + 32*n + la] =
            red[mt][row][32*n + la] + acc[n][reg];
      }
  }
}

// ---------------------------------------------------------------------------
// z = O_irr + O_sol + sum_k zpart[k] + b_total
__global__ __launch_bounds__(256) void k_combine(const float* __restrict__ ws,
                                                 float* __restrict__ z) {
  const int i = blockIdx.x * 256 + threadIdx.x;
  const int col = i & 127;
  float acc = ws[BT_OFF + col] + ws[OI_OFF + i] + ws[OS_OFF + i];
  #pragma unroll
  for (int kz = 0; kz < 8; ++kz) acc += ws[ZP_OFF + kz*NN*128 + i];
  z[i] = acc;
}

// ---------------------------------------------------------------------------
extern "C" void kernel_launch(void* const* d_in, const int* in_sizes, int n_in,
                              void* d_out, int out_size, void* d_ws, size_t ws_size,
                              hipStream_t stream) {
  const float* x       = (const float*)d_in[0];
  const float* Lu      = (const float*)d_in[1];
  const float* Ld      = (const float*)d_in[2];
  const float* P       = (const float*)d_in[3];
  const float* Wi_w    = (const float*)d_in[4];
  const float* Wi_b    = (const float*)d_in[5];
  const float* Ws_w    = (const float*)d_in[6];
  const float* Ws_b    = (const float*)d_in[7];
  const float* Wh_w    = (const float*)d_in[8];
  const float* Wh_b    = (const float*)d_in[9];
  const float* att_irr = (const float*)d_in[10];
  const float* att_sol = (const float*)d_in[11];
  float* z  = (float*)d_out;
  float* ws = (float*)d_ws;
  unsigned short* idxbuf = (unsigned short*)((char*)d_ws + IDX_BYTE_OFF);
  int*            cntbuf = (int*)((char*)d_ws + CNT_BYTE_OFF);
  float*          zpart  = ws + ZP_OFF;
  unsigned short* xth    = (unsigned short*)(ws + XWH_OFF);           // 1 MB
  unsigned short* xtl    = xth + (size_t)128 * NN;                    // 1 MB

  k_prep<<<1, 128, 0, stream>>>(Wi_w, Wi_b, Ws_w, Ws_b, Wh_b, att_irr, att_sol, ws);
  k_pre2<<<1152, 256, 0, stream>>>(x, Wh_w, ws, xth, xtl);
  k_spmm_emit<<<2 * NN, 256, 0, stream>>>(Ld, Lu, x, ws, idxbuf, cntbuf);
  {
    dim3 g(128, 2);
    k_ugemm<<<g, 256, 0, stream>>>(x, Wi_w, Ws_w, ws);
  }
  k_attn<<<2 * NN, 256, 0, stream>>>(Ld, Lu, ws, idxbuf, cntbuf);
  {
    dim3 g(64, 8);
    k_pgemm<<<g, 256, 0, stream>>>(P, xth, xtl, zpart);
  }
  k_combine<<<NN * 128 / 256, 256, 0, stream>>>(ws, z);
}

// Round 6
// 353.839 us; speedup vs baseline: 1.0969x; 1.0245x over previous
//
#include <hip/hip_runtime.h>

#define NN 4096
#define IDX_CAP 512
#define SEG_CAP 160
#define SLOPE 0.2f

typedef float f4_t __attribute__((ext_vector_type(4)));
typedef __bf16 bf8v __attribute__((ext_vector_type(8)));
typedef float f32x16 __attribute__((ext_vector_type(16)));

// ---- workspace layout (float offsets unless noted) ----
#define V_OFF     0                        // v1i,v2i,v1s,v2s : 4*128
#define C_OFF     512                      // 4 score constants
#define BT_OFF    516                      // b_total[128]
#define S_OFF     1024                     // s1i,s2i,s1s,s2s : 4*4096
#define HXI_OFF   32768                    // Ld@x   [4096,128]
#define HXS_OFF   (HXI_OFF + NN*128)       // Lu@x
#define UI_OFF    (HXS_OFF + NN*128)       // x@Wi0 + Hxi@Wi1
#define US_OFF    (UI_OFF + NN*128)        // x@Ws0 + Hxs@Ws1
#define XWH_OFF   (US_OFF + NN*128)        // REUSED: xwhT hi/lo bf16 MFMA-fragment buffers
#define OI_OFF    (XWH_OFF + NN*128)       // alpha_irr @ U_irr
#define OS_OFF    (OI_OFF + NN*128)        // alpha_sol @ U_sol
#define ZP_OFF    (OS_OFF + NN*128)        // P@xWh split-K partials: 8 * [4096,128]
#define WS_FLOATS (ZP_OFF + 8*NN*128)
#define IDX_BYTE_OFF ((size_t)WS_FLOATS * 4)                  // u16 idx lists: 2*4096*512
#define CNT_BYTE_OFF (IDX_BYTE_OFF + (size_t)2*NN*IDX_CAP*2)  // int counts: 2*4096

// Pad map: insert 4 floats after every 32 -> float4 reads at stride 8 floats
// drop from 4-way to 2-way bank aliasing (2-way is free, m136).
#define XI(c)   ((c) + (((c) >> 5) << 2))   // [0,128) -> [0,140)

// XCD-aware (row,branch) mapping for the sparse kernels.
#define MAP_BR(bid)   (((bid) >> 2) & 1)
#define MAP_ROW(bid)  ((((bid) >> 3) << 2) | ((bid) & 3))

// MFMA-fragment layout for xwhT: element (col c of z, k-index k) lives at
// frag[(k>>4)*2048 + (c>>5)*512 + ((c&31) + 32*((k>>3)&1))*8 + (k&7)].
// A wave's B-load for (K-step, n-tile) is then ONE contiguous 1 KB read.
#define FRAG(c, k) ((size_t)((k) >> 4) * 2048 + (size_t)((c) >> 5) * 512 \
                    + (size_t)((((c) & 31) + 32 * (((k) >> 3) & 1)) * 8 + ((k) & 7)))

// bf16 round-to-nearest-even helpers (bit math; no HIP bf16 header dependence)
__device__ __forceinline__ unsigned short f2bf(float x) {
  unsigned u = __float_as_uint(x);
  return (unsigned short)((u + 0x7FFFu + ((u >> 16) & 1u)) >> 16);
}
__device__ __forceinline__ float bf2f(unsigned short h) {
  return __uint_as_float(((unsigned)h) << 16);
}
union BFU { unsigned short u[8]; bf8v v; };

// ---------------------------------------------------------------------------
// Prep: v-vectors so s1[i] = x[i,:]·v + c, b_total.
__global__ __launch_bounds__(128) void k_prep(
    const float* __restrict__ Wi_w, const float* __restrict__ Wi_b,
    const float* __restrict__ Ws_w, const float* __restrict__ Ws_b,
    const float* __restrict__ Wh_b, const float* __restrict__ att_irr,
    const float* __restrict__ att_sol, float* __restrict__ ws) {
  const int t = threadIdx.x;
  float v1i = 0.f, v2i = 0.f, v1s = 0.f, v2s = 0.f;
  for (int j = 0; j < 2; ++j) {
    for (int o = 0; o < 128; ++o) {
      const float wi = Wi_w[j*16384 + t*128 + o];
      const float wv = Ws_w[j*16384 + t*128 + o];
      v1i += wi * att_irr[j*128 + o];
      v2i += wi * att_irr[256 + j*128 + o];
      v1s += wv * att_sol[j*128 + o];
      v2s += wv * att_sol[256 + j*128 + o];
    }
  }
  ws[V_OFF + t]       = v1i;
  ws[V_OFF + 128 + t] = v2i;
  ws[V_OFF + 256 + t] = v1s;
  ws[V_OFF + 384 + t] = v2s;
  ws[BT_OFF + t] = Wi_b[t] + Wi_b[128 + t] + Ws_b[t] + Ws_b[128 + t] + Wh_b[t];
  if (t < 4) {
    const float* bb = (t < 2) ? Wi_b : Ws_b;
    const float* aa = ((t < 2) ? att_irr : att_sol) + ((t & 1) ? 256 : 0);
    float c = 0.f;
    for (int k = 0; k < 256; ++k) c += bb[k] * aa[k];
    ws[C_OFF + t] = c;
  }
}

// ---------------------------------------------------------------------------
// Fused pre-pass: blocks 0..127 compute xWh = x@Wh -> write bf16 hi/lo in
// MFMA-fragment order (feeds k_pgemm); blocks 128..1151 compute scores.
__global__ __launch_bounds__(256) void k_pre2(
    const float* __restrict__ x, const float* __restrict__ Wh_w,
    float* __restrict__ ws, unsigned short* __restrict__ xth,
    unsigned short* __restrict__ xtl) {
  __shared__ __align__(16) float At[32][33];
  __shared__ __align__(16) float Wt[32][144];
  const int t = threadIdx.x;

  if (blockIdx.x < 128) {
    const int rb = blockIdx.x;
    const int rg = t >> 4, cg = t & 15;
    const int r0 = rb * 32;
    float acc[2][8];
    #pragma unroll
    for (int i = 0; i < 2; ++i)
      #pragma unroll
      for (int j = 0; j < 8; ++j) acc[i][j] = 0.f;
    for (int k0 = 0; k0 < 128; k0 += 32) {
      __syncthreads();
      {
        const int row = t >> 3, kq = t & 7;
        const float4 av = *(const float4*)&x[(r0 + row)*128 + k0 + kq*4];
        At[row][kq*4+0] = av.x; At[row][kq*4+1] = av.y;
        At[row][kq*4+2] = av.z; At[row][kq*4+3] = av.w;
      }
      #pragma unroll
      for (int l = 0; l < 4; ++l) {
        const int idx = t + l*256;
        const int kr = idx >> 5, c4 = idx & 31;
        const float4 wv = *(const float4*)&Wh_w[(k0 + kr)*128 + c4*4];
        *(float4*)&Wt[kr][XI(c4*4)] = wv;
      }
      __syncthreads();
      #pragma unroll
      for (int k = 0; k < 32; ++k) {
        const float a0 = At[rg*2 + 0][k];
        const float a1 = At[rg*2 + 1][k];
        const float4 b0 = *(const float4*)&Wt[k][XI(cg*8)];
        const float4 b1 = *(const float4*)&Wt[k][XI(cg*8 + 4)];
        acc[0][0] += a0*b0.x; acc[0][1] += a0*b0.y; acc[0][2] += a0*b0.z; acc[0][3] += a0*b0.w;
        acc[0][4] += a0*b1.x; acc[0][5] += a0*b1.y; acc[0][6] += a0*b1.z; acc[0][7] += a0*b1.w;
        acc[1][0] += a1*b0.x; acc[1][1] += a1*b0.y; acc[1][2] += a1*b0.z; acc[1][3] += a1*b0.w;
        acc[1][4] += a1*b1.x; acc[1][5] += a1*b1.y; acc[1][6] += a1*b1.z; acc[1][7] += a1*b1.w;
      }
    }
    #pragma unroll
    for (int i = 0; i < 2; ++i) {
      const int r = r0 + rg*2 + i;       // r = k-index of pgemm
      #pragma unroll
      for (int j = 0; j < 8; ++j) {
        const int c = cg*8 + j;          // c = output column
        const float val = acc[i][j];
        const unsigned short h = f2bf(val);
        const unsigned short l = f2bf(val - bf2f(h));
        const size_t fa = FRAG(c, r);
        xth[fa] = h;
        xtl[fa] = l;
      }
    }
  } else {
    const int wave = t >> 6, lane = t & 63;
    const int row = (blockIdx.x - 128) * 4 + wave;
    const float* v = ws + V_OFF;
    const float x0 = x[row*128 + lane];
    const float x1 = x[row*128 + 64 + lane];
    float p0 = x0 * v[lane]       + x1 * v[64 + lane];
    float p1 = x0 * v[128 + lane] + x1 * v[192 + lane];
    float p2 = x0 * v[256 + lane] + x1 * v[320 + lane];
    float p3 = x0 * v[384 + lane] + x1 * v[448 + lane];
    #pragma unroll
    for (int off = 32; off; off >>= 1) {
      p0 += __shfl_down(p0, off);
      p1 += __shfl_down(p1, off);
      p2 += __shfl_down(p2, off);
      p3 += __shfl_down(p3, off);
    }
    if (lane == 0) {
      ws[S_OFF + row]          = p0 + ws[C_OFF + 0];
      ws[S_OFF + NN + row]     = p1 + ws[C_OFF + 1];
      ws[S_OFF + 2*NN + row]   = p2 + ws[C_OFF + 2];
      ws[S_OFF + 3*NN + row]   = p3 + ws[C_OFF + 3];
    }
  }
}

// ---------------------------------------------------------------------------
// Sparse row pass (round-3 form): per-wave register-base compaction, nt scan,
// float4 pair-gather, XCD-aware branch mapping.
__global__ __launch_bounds__(256) void k_spmm_emit(
    const float* __restrict__ Ld, const float* __restrict__ Lu,
    const float* __restrict__ x, float* __restrict__ ws,
    unsigned short* __restrict__ idxbuf, int* __restrict__ cntbuf) {
  const int bid = blockIdx.x;
  const int br  = MAP_BR(bid);
  const int row = MAP_ROW(bid);
  const float* __restrict__ Lrow = (br ? Lu : Ld) + (size_t)row * NN;
  float* __restrict__ Hx = ws + (br ? HXS_OFF : HXI_OFF);
  unsigned short* __restrict__ idxg = idxbuf + (size_t)(br*NN + row) * IDX_CAP;
  const int t = threadIdx.x;
  const int w = t >> 6, lane = t & 63;
  const unsigned long long lmask = (1ull << lane) - 1ull;

  __shared__ short jseg[4][SEG_CAP];
  __shared__ float vseg[4][SEG_CAP];
  __shared__ int   wcnt[4];
  __shared__ int   off[5];
  __shared__ short jl[IDX_CAP];
  __shared__ float vl[IDX_CAP];
  __shared__ float red[4][128];

  const f4_t* __restrict__ Lrow4 = (const f4_t*)Lrow;
  f4_t lv[4];
  #pragma unroll
  for (int i = 0; i < 4; ++i) lv[i] = __builtin_nontemporal_load(&Lrow4[i*256 + t]);

  int base = 0;
  #pragma unroll
  for (int i = 0; i < 4; ++i) {
    #pragma unroll
    for (int c = 0; c < 4; ++c) {
      const float v = lv[i][c];
      const unsigned long long bm = __ballot(v != 0.f);
      if (v != 0.f) {
        const int pos = base + (int)__popcll(bm & lmask);
        if (pos < SEG_CAP) {
          jseg[w][pos] = (short)((i*256 + t)*4 + c);
          vseg[w][pos] = v;
        }
      }
      base += (int)__popcll(bm);
    }
  }
  if (lane == 0) wcnt[w] = base;
  __syncthreads();
  if (t == 0) {
    int o = 0, ov = 0;
    #pragma unroll
    for (int s = 0; s < 4; ++s) { off[s] = o; ov |= (wcnt[s] > SEG_CAP); o += wcnt[s]; }
    off[4] = (ov || o > IDX_CAP) ? (IDX_CAP + 1) : o;
    cntbuf[br*NN + row] = off[4];
  }
  __syncthreads();
  const int m = off[4];

  if (m <= IDX_CAP) {
    const int o = off[w], c = wcnt[w];
    for (int k = lane; k < c; k += 64) {
      const short j = jseg[w][k];
      jl[o + k] = j;
      vl[o + k] = vseg[w][k];
      idxg[o + k] = (unsigned short)j;
    }
  }
  __syncthreads();

  if (m <= IDX_CAP) {
    const f4_t* __restrict__ x4 = (const f4_t*)x;
    const int li = lane & 31, half = lane >> 5;
    f4_t acc = {0.f, 0.f, 0.f, 0.f};
    int p = w;
    for (; 2*(p + 12) + 1 < m; p += 16) {
      const int q0 = 2*p + half, q1 = 2*(p+4) + half,
                q2 = 2*(p+8) + half, q3 = 2*(p+12) + half;
      const int j0 = jl[q0], j1 = jl[q1], j2 = jl[q2], j3 = jl[q3];
      const float v0 = vl[q0], v1 = vl[q1], v2 = vl[q2], v3 = vl[q3];
      const f4_t g0 = x4[j0*32 + li];
      const f4_t g1 = x4[j1*32 + li];
      const f4_t g2 = x4[j2*32 + li];
      const f4_t g3 = x4[j3*32 + li];
      acc += v0*g0; acc += v1*g1; acc += v2*g2; acc += v3*g3;
    }
    for (; 2*p < m; p += 4) {
      const int q = 2*p + half;
      if (q < m) acc += vl[q] * x4[jl[q]*32 + li];
    }
    #pragma unroll
    for (int c = 0; c < 4; ++c) acc[c] += __shfl_xor(acc[c], 32);
    if (half == 0) {
      red[w][li*4+0] = acc[0]; red[w][li*4+1] = acc[1];
      red[w][li*4+2] = acc[2]; red[w][li*4+3] = acc[3];
    }
  } else {
    const float2* __restrict__ x2 = (const float2*)x;
    float acc0 = 0.f, acc1 = 0.f;
    for (int j = w*1024; j < (w+1)*1024; ++j) {
      const float v = Lrow[j];
      if (v != 0.f) {
        const float2 g = x2[j*64 + lane];
        acc0 += v*g.x; acc1 += v*g.y;
      }
    }
    red[w][lane*2]     = acc0;
    red[w][lane*2 + 1] = acc1;
  }
  __syncthreads();
  if (t < 128)
    Hx[row*128 + t] = red[0][t] + red[1][t] + red[2][t] + red[3][t];
}

// ---------------------------------------------------------------------------
// U-GEMMs: U_irr = x@Wi0 + Hxi@Wi1 ; U_sol = x@Ws0 + Hxs@Ws1 (padded Wt).
__global__ __launch_bounds__(256) void k_ugemm(
    const float* __restrict__ x, const float* __restrict__ Wi_w,
    const float* __restrict__ Ws_w, float* __restrict__ ws) {
  const int rb = blockIdx.x;
  const int sel = blockIdx.y;      // 0:U_irr 1:U_sol
  const float* A[2]; const float* W[2]; float* out;
  if (sel == 0) { A[0]=x; W[0]=Wi_w; A[1]=ws+HXI_OFF; W[1]=Wi_w+16384; out=ws+UI_OFF; }
  else          { A[0]=x; W[0]=Ws_w; A[1]=ws+HXS_OFF; W[1]=Ws_w+16384; out=ws+US_OFF; }

  __shared__ __align__(16) float At[32][33];
  __shared__ __align__(16) float Wt[32][144];
  const int t = threadIdx.x;
  const int rg = t >> 4, cg = t & 15;
  const int r0 = rb * 32;
  float acc[2][8];
  #pragma unroll
  for (int i = 0; i < 2; ++i)
    #pragma unroll
    for (int j = 0; j < 8; ++j) acc[i][j] = 0.f;

  for (int ps = 0; ps < 2; ++ps) {
    const float* __restrict__ Ap = A[ps];
    const float* __restrict__ Wp = W[ps];
    for (int k0 = 0; k0 < 128; k0 += 32) {
      __syncthreads();
      {
        const int row = t >> 3, kq = t & 7;
        const float4 av = *(const float4*)&Ap[(r0 + row)*128 + k0 + kq*4];
        At[row][kq*4+0] = av.x; At[row][kq*4+1] = av.y;
        At[row][kq*4+2] = av.z; At[row][kq*4+3] = av.w;
      }
      #pragma unroll
      for (int l = 0; l < 4; ++l) {
        const int idx = t + l*256;
        const int kr = idx >> 5, c4 = idx & 31;
        const float4 wv = *(const float4*)&Wp[(k0 + kr)*128 + c4*4];
        *(float4*)&Wt[kr][XI(c4*4)] = wv;
      }
      __syncthreads();
      #pragma unroll
      for (int k = 0; k < 32; ++k) {
        const float a0 = At[rg*2 + 0][k];
        const float a1 = At[rg*2 + 1][k];
        const float4 b0 = *(const float4*)&Wt[k][XI(cg*8)];
        const float4 b1 = *(const float4*)&Wt[k][XI(cg*8 + 4)];
        acc[0][0] += a0*b0.x; acc[0][1] += a0*b0.y; acc[0][2] += a0*b0.z; acc[0][3] += a0*b0.w;
        acc[0][4] += a0*b1.x; acc[0][5] += a0*b1.y; acc[0][6] += a0*b1.z; acc[0][7] += a0*b1.w;
        acc[1][0] += a1*b0.x; acc[1][1] += a1*b0.y; acc[1][2] += a1*b0.z; acc[1][3] += a1*b0.w;
        acc[1][4] += a1*b1.x; acc[1][5] += a1*b1.y; acc[1][6] += a1*b1.z; acc[1][7] += a1*b1.w;
      }
    }
  }
  #pragma unroll
  for (int i = 0; i < 2; ++i) {
    const int r = r0 + rg*2 + i;
    #pragma unroll
    for (int j = 0; j < 8; ++j) out[r*128 + cg*8 + j] = acc[i][j];
  }
}

// ---------------------------------------------------------------------------
// Masked-softmax attention (round-3 form): float4 pair-gather, XCD mapping.
__global__ __launch_bounds__(256) void k_attn(
    const float* __restrict__ Ld, const float* __restrict__ Lu,
    float* __restrict__ ws, const unsigned short* __restrict__ idxbuf,
    const int* __restrict__ cntbuf) {
  const int bid = blockIdx.x;
  const int br  = MAP_BR(bid);
  const int row = MAP_ROW(bid);
  const float* __restrict__ U = ws + (br ? US_OFF : UI_OFF);
  float* __restrict__ O = ws + (br ? OS_OFF : OI_OFF);
  const float s1 = ws[S_OFF + (br ? 2*NN : 0) + row];
  const float* __restrict__ s2a = ws + S_OFF + (br ? 3*NN : NN);
  const int cnt = cntbuf[br*NN + row];
  const int t = threadIdx.x;
  const int w = t >> 6, lane = t & 63;

  __shared__ int   jl[IDX_CAP];
  __shared__ float el[IDX_CAP];
  __shared__ float red[4][128];
  __shared__ float rsum[256];
  __shared__ float dsh[4];

  if (cnt > 0 && cnt <= IDX_CAP) {
    const unsigned short* __restrict__ idx = idxbuf + (size_t)(br*NN + row) * IDX_CAP;
    float dpart = 0.f;
    for (int p = t; p < cnt; p += 256) {
      const int j = idx[p];
      const float sc = s1 + s2a[j];
      const float e = expf(sc >= 0.f ? sc : SLOPE * sc);
      jl[p] = j; el[p] = e; dpart += e;
    }
    rsum[t] = dpart;
    __syncthreads();
    if (t < 128) rsum[t] += rsum[t + 128];
    __syncthreads();
    if (t < 64) {
      float v = rsum[t] + rsum[t + 64];
      #pragma unroll
      for (int off = 32; off; off >>= 1) v += __shfl_down(v, off);
      if (t == 0) dsh[0] = v;
    }
    __syncthreads();
    const float den = dsh[0];
    const f4_t* __restrict__ U4 = (const f4_t*)U;
    const int li = lane & 31, half = lane >> 5;
    f4_t acc = {0.f, 0.f, 0.f, 0.f};
    int p = w;
    for (; 2*(p + 12) + 1 < cnt; p += 16) {
      const int q0 = 2*p + half, q1 = 2*(p+4) + half,
                q2 = 2*(p+8) + half, q3 = 2*(p+12) + half;
      const int j0 = jl[q0], j1 = jl[q1], j2 = jl[q2], j3 = jl[q3];
      const float e0 = el[q0], e1 = el[q1], e2 = el[q2], e3 = el[q3];
      const f4_t g0 = U4[j0*32 + li];
      const f4_t g1 = U4[j1*32 + li];
      const f4_t g2 = U4[j2*32 + li];
      const f4_t g3 = U4[j3*32 + li];
      acc += e0*g0; acc += e1*g1; acc += e2*g2; acc += e3*g3;
    }
    for (; 2*p < cnt; p += 4) {
      const int q = 2*p + half;
      if (q < cnt) acc += el[q] * U4[jl[q]*32 + li];
    }
    #pragma unroll
    for (int c = 0; c < 4; ++c) acc[c] += __shfl_xor(acc[c], 32);
    if (half == 0) {
      red[w][li*4+0] = acc[0]; red[w][li*4+1] = acc[1];
      red[w][li*4+2] = acc[2]; red[w][li*4+3] = acc[3];
    }
    __syncthreads();
    if (t < 128)
      O[row*128 + t] = (red[0][t] + red[1][t] + red[2][t] + red[3][t]) / den;
  } else if (cnt == 0) {
    const float2* __restrict__ U2 = (const float2*)U;
    float acc0 = 0.f, acc1 = 0.f;
    for (int j = w*1024; j < (w+1)*1024; ++j) {
      const float2 g = U2[j*64 + lane];
      acc0 += g.x; acc1 += g.y;
    }
    red[w][lane*2]     = acc0;
    red[w][lane*2 + 1] = acc1;
    __syncthreads();
    if (t < 128)
      O[row*128 + t] = (red[0][t] + red[1][t] + red[2][t] + red[3][t]) * (1.f / NN);
  } else {
    const float* __restrict__ Lrow = (br ? Lu : Ld) + (size_t)row * NN;
    const float2* __restrict__ U2 = (const float2*)U;
    float acc0 = 0.f, acc1 = 0.f, dp = 0.f;
    for (int j = w*1024; j < (w+1)*1024; ++j) {
      const float v = Lrow[j];
      if (v != 0.f) {
        const float sc = s1 + s2a[j];
        const float e = expf(sc >= 0.f ? sc : SLOPE * sc);
        const float2 g = U2[j*64 + lane];
        acc0 += e*g.x; acc1 += e*g.y;
        dp += e;
      }
    }
    if (lane == 0) dsh[w] = dp;
    red[w][lane*2]     = acc0;
    red[w][lane*2 + 1] = acc1;
    __syncthreads();
    const float den = dsh[0] + dsh[1] + dsh[2] + dsh[3];
    if (t < 128)
      O[row*128 + t] = (red[0][t] + red[1][t] + red[2][t] + red[3][t]) / den;
  }
}

// ---------------------------------------------------------------------------
// Dense P @ xWh via MFMA, v2: BM=32, grid (128, 8) -> 4 blocks/CU; each of
// the 4 waves owns a 128-wide K-quarter (8 steps of 16). B loaded from the
// fragment-ordered xth/xtl (1 KB coalesced L2 hits); A nt-loaded from P with
// one-step software prefetch. D-layout per m74/m101 (verified):
// col=lane&31, row=(reg&3)+8*(reg>>2)+4*(lane>>5).
__global__ __launch_bounds__(256) void k_pgemm(
    const float* __restrict__ P, const unsigned short* __restrict__ xth,
    const unsigned short* __restrict__ xtl, float* __restrict__ zpart) {
  const int t = threadIdx.x;
  const int w = t >> 6, lane = t & 63;
  const int la = lane & 31;
  const int koff = (lane >> 5) * 8;
  const int r0 = blockIdx.x * 32;
  const int kz = blockIdx.y;
  const int kb = kz * 512 + w * 128;     // this wave's 128-wide K-quarter

  f32x16 acc[4];
  #pragma unroll
  for (int n = 0; n < 4; ++n)
    #pragma unroll
    for (int e = 0; e < 16; ++e) acc[n][e] = 0.f;

  const float* __restrict__ arow = P + (size_t)(r0 + la) * NN + kb + koff;
  const unsigned short* __restrict__ bh_base = xth + (size_t)kb * 128 + lane * 8;
  const unsigned short* __restrict__ bl_base = xtl + (size_t)kb * 128 + lane * 8;

  f4_t a0 = __builtin_nontemporal_load((const f4_t*)arow);
  f4_t a1 = __builtin_nontemporal_load((const f4_t*)(arow + 4));
  for (int s = 0; s < 8; ++s) {
    f4_t na0 = a0, na1 = a1;
    if (s < 7) {
      na0 = __builtin_nontemporal_load((const f4_t*)(arow + (s + 1) * 16));
      na1 = __builtin_nontemporal_load((const f4_t*)(arow + (s + 1) * 16 + 4));
    }
    BFU ah, al;
    #pragma unroll
    for (int i = 0; i < 8; ++i) {
      const float f = (i < 4) ? a0[i] : a1[i - 4];
      const unsigned short h = f2bf(f);
      ah.u[i] = h;
      al.u[i] = f2bf(f - bf2f(h));
    }
    const unsigned short* __restrict__ bh_s = bh_base + s * 2048;
    const unsigned short* __restrict__ bl_s = bl_base + s * 2048;
    #pragma unroll
    for (int n = 0; n < 4; ++n) {
      const bf8v bh = *(const bf8v*)(bh_s + n * 512);
      const bf8v bl = *(const bf8v*)(bl_s + n * 512);
      acc[n] = __builtin_amdgcn_mfma_f32_32x32x16_bf16(ah.v, bh, acc[n], 0, 0, 0);
      acc[n] = __builtin_amdgcn_mfma_f32_32x32x16_bf16(al.v, bh, acc[n], 0, 0, 0);
      acc[n] = __builtin_amdgcn_mfma_f32_32x32x16_bf16(ah.v, bl, acc[n], 0, 0, 0);
    }
    a0 = na0; a1 = na1;
  }

  // reduce 4 K-quarter waves: slabs red[0],red[1], then add, then combine.
  __shared__ float red[2][32][128];
  if (w < 2) {
    #pragma unroll
    for (int n = 0; n < 4; ++n)
      #pragma unroll
      for (int reg = 0; reg < 16; ++reg) {
        const int row = (reg & 3) + 8*(reg >> 2) + 4*(lane >> 5);
        red[w][row][32*n + la] = acc[n][reg];
      }
  }
  __syncthreads();
  if (w >= 2) {
    #pragma unroll
    for (int n = 0; n < 4; ++n)
      #pragma unroll
      for (int reg = 0; reg < 16; ++reg) {
        const int row = (reg & 3) + 8*(reg >> 2) + 4*(lane >> 5);
        red[w - 2][row][32*n + la] += acc[n][reg];
      }
  }
  __syncthreads();
  float* __restrict__ zp = zpart + (size_t)kz * NN * 128;
  #pragma unroll
  for (int i = 0; i < 8; ++i) {
    const int row = w * 8 + i;
    zp[(size_t)(r0 + row) * 128 + lane]      = red[0][row][lane]      + red[1][row][lane];
    zp[(size_t)(r0 + row) * 128 + 64 + lane] = red[0][row][64 + lane] + red[1][row][64 + lane];
  }
}

// ---------------------------------------------------------------------------
// z = O_irr + O_sol + sum_k zpart[k] + b_total
__global__ __launch_bounds__(256) void k_combine(const float* __restrict__ ws,
                                                 float* __restrict__ z) {
  const int i = blockIdx.x * 256 + threadIdx.x;
  const int col = i & 127;
  float acc = ws[BT_OFF + col] + ws[OI_OFF + i] + ws[OS_OFF + i];
  #pragma unroll
  for (int kz = 0; kz < 8; ++kz) acc += ws[ZP_OFF + kz*NN*128 + i];
  z[i] = acc;
}

// ---------------------------------------------------------------------------
extern "C" void kernel_launch(void* const* d_in, const int* in_sizes, int n_in,
                              void* d_out, int out_size, void* d_ws, size_t ws_size,
                              hipStream_t stream) {
  const float* x       = (const float*)d_in[0];
  const float* Lu      = (const float*)d_in[1];
  const float* Ld      = (const float*)d_in[2];
  const float* P       = (const float*)d_in[3];
  const float* Wi_w    = (const float*)d_in[4];
  const float* Wi_b    = (const float*)d_in[5];
  const float* Ws_w    = (const float*)d_in[6];
  const float* Ws_b    = (const float*)d_in[7];
  const float* Wh_w    = (const float*)d_in[8];
  const float* Wh_b    = (const float*)d_in[9];
  const float* att_irr = (const float*)d_in[10];
  const float* att_sol = (const float*)d_in[11];
  float* z  = (float*)d_out;
  float* ws = (float*)d_ws;
  unsigned short* idxbuf = (unsigned short*)((char*)d_ws + IDX_BYTE_OFF);
  int*            cntbuf = (int*)((char*)d_ws + CNT_BYTE_OFF);
  float*          zpart  = ws + ZP_OFF;
  unsigned short* xth    = (unsigned short*)(ws + XWH_OFF);           // 1 MB
  unsigned short* xtl    = xth + (size_t)128 * NN;                    // 1 MB

  k_prep<<<1, 128, 0, stream>>>(Wi_w, Wi_b, Ws_w, Ws_b, Wh_b, att_irr, att_sol, ws);
  k_pre2<<<1152, 256, 0, stream>>>(x, Wh_w, ws, xth, xtl);
  k_spmm_emit<<<2 * NN, 256, 0, stream>>>(Ld, Lu, x, ws, idxbuf, cntbuf);
  {
    dim3 g(128, 2);
    k_ugemm<<<g, 256, 0, stream>>>(x, Wi_w, Ws_w, ws);
  }
  k_attn<<<2 * NN, 256, 0, stream>>>(Ld, Lu, ws, idxbuf, cntbuf);
  {
    dim3 g(128, 8);
    k_pgemm<<<g, 256, 0, stream>>>(P, xth, xtl, zpart);
  }
  k_combine<<<NN * 128 / 256, 256, 0, stream>>>(ws, z);
}